// Round 3
// baseline (688.066 us; speedup 1.0000x reference)
//
#include <hip/hip_runtime.h>
#include <math.h>

// N=2, K=20 -> 40 images; C=64 channels; 16x16 images (256 px).
#define NIMG 40
#define PXI  256
#define CH   64
#define SB_ELEM (NIMG * PXI * CH)   // 655360 elems per activation tensor

typedef __bf16 bf16x8 __attribute__((ext_vector_type(8)));
typedef float  f32x4  __attribute__((ext_vector_type(4)));

static __device__ __forceinline__ unsigned short f2bf(float f) {
    unsigned u = __builtin_bit_cast(unsigned, f);
    u += 0x7fffu + ((u >> 16) & 1u);          // RNE
    return (unsigned short)(u >> 16);
}
static __device__ __forceinline__ float bfu2f(unsigned hs) {  // bf16 bits in low 16
    unsigned u = (hs & 0xffffu) << 16;
    return __builtin_bit_cast(float, u);
}

// ---------------------------------------------------------------------------
// Core: one wave computes rows {y0, y0+1} (two 16-px tiles) x all 4 oc-tiles
// of a 3x3 SAME conv, from LDS Z (bf16, swizzled [pix][ci]) and Wt bf16
// [9][64 oc][64 ci]. Accumulates into acc[2][4] (f32x4 each).
// LDS 16B-slot index = pix*8 + (g ^ (pix&7)), g = ci/8.  (T2 swizzle)
// ---------------------------------------------------------------------------
static __device__ __forceinline__ void conv_tiles2(const uint4* __restrict__ ldsZ,
                                                   const uint4* __restrict__ Wt,
                                                   int y0, int lane, f32x4 acc[2][4])
{
    const int l15 = lane & 15;
    const int l4  = lane >> 4;
#pragma unroll
    for (int khalf = 0; khalf < 2; ++khalf) {
        const int g   = khalf * 4 + l4;          // 16B group of this lane's k-slice
        const int ciu = khalf * 4 + l4;
#pragma unroll
        for (int kk = 0; kk < 9; ++kk) {
            const int ky = kk / 3 - 1;
            const int kx = kk % 3 - 1;
            bf16x8 bfrag[4];
#pragma unroll
            for (int oct = 0; oct < 4; ++oct) {
                uint4 wv = Wt[(kk * 64 + oct * 16 + l15) * 8 + ciu];
                bfrag[oct] = __builtin_bit_cast(bf16x8, wv);
            }
#pragma unroll
            for (int r = 0; r < 2; ++r) {
                const int yy = y0 + r + ky;
                const int xx = l15 + kx;
                const bool inb = ((unsigned)yy < 16u) && ((unsigned)xx < 16u);
                const int pix = inb ? (yy * 16 + xx) : 0;
                uint4 av = ldsZ[pix * 8 + (g ^ (pix & 7))];
                if (!inb) { av.x = 0u; av.y = 0u; av.z = 0u; av.w = 0u; }
                bf16x8 afrag = __builtin_bit_cast(bf16x8, av);
#pragma unroll
                for (int oct = 0; oct < 4; ++oct)
                    acc[r][oct] = __builtin_amdgcn_mfma_f32_16x16x32_bf16(
                        afrag, bfrag[oct], acc[r][oct], 0, 0, 0);
            }
        }
    }
}

// ---------------------------------------------------------------------------
// Generic MFMA conv: X bf16 [img][256][64] -> out bf16 [img][256][64]
// ---------------------------------------------------------------------------
struct ConvDesc {
    const uint4* X;
    const uint4* W;
    const float* bias;      // nullptr -> no bias
    unsigned short* out;
    int relu;
};
struct ConvBatch { ConvDesc d[6]; };

__global__ __launch_bounds__(512)
void conv_mfma_k(ConvBatch cb)
{
    __shared__ uint4 ldsZ[2048];
    const ConvDesc d = cb.d[blockIdx.y];
    const int img = blockIdx.x;
    const int tid = threadIdx.x;

    const uint4* Xi = d.X + img * 2048;
#pragma unroll
    for (int i = 0; i < 4; ++i) {
        int u = tid * 4 + i;
        int px = u >> 3, g = u & 7;
        ldsZ[px * 8 + (g ^ (px & 7))] = Xi[u];
    }
    __syncthreads();

    const int lane = tid & 63, wv = tid >> 6;
    const int l15 = lane & 15, l4 = lane >> 4;
    f32x4 zz = {0.f, 0.f, 0.f, 0.f};
    f32x4 acc[2][4];
#pragma unroll
    for (int r = 0; r < 2; ++r)
#pragma unroll
        for (int o = 0; o < 4; ++o) acc[r][o] = zz;

    conv_tiles2(ldsZ, d.W, wv * 2, lane, acc);

#pragma unroll
    for (int oct = 0; oct < 4; ++oct) {
        const int oc = oct * 16 + l15;
        const float b = d.bias ? d.bias[oc] : 0.f;
#pragma unroll
        for (int r = 0; r < 2; ++r)
#pragma unroll
            for (int e = 0; e < 4; ++e) {
                float v = acc[r][oct][e] + b;
                if (d.relu) v = fmaxf(v, 0.f);
                const int px = (wv * 2 + r) * 16 + l4 * 4 + e;
                d.out[(img * PXI + px) * CH + oc] = f2bf(v);
            }
    }
}

// ---------------------------------------------------------------------------
// Pair kernel (no atomics): block bi -> imgb = bi/10, split s = bi%10 (2 a's).
// accout = sum over the 2 sources of msg*sigmoid(gate); written as bf16 to
// partials[s][imgb][px][oc].
// ---------------------------------------------------------------------------
static __device__ __forceinline__ unsigned radd2(unsigned a, unsigned b) {
    float a0 = __builtin_bit_cast(float, a << 16);
    float a1 = __builtin_bit_cast(float, a & 0xffff0000u);
    float b0 = __builtin_bit_cast(float, b << 16);
    float b1 = __builtin_bit_cast(float, b & 0xffff0000u);
    float s0 = fmaxf(a0 + b0, 0.f);
    float s1 = fmaxf(a1 + b1, 0.f);
    return (unsigned)f2bf(s0) | ((unsigned)f2bf(s1) << 16);
}

static __device__ __forceinline__ void build_z(uint4* ldsZ, const uint4* __restrict__ A,
                                               const uint4* __restrict__ B, int tid)
{
#pragma unroll
    for (int i = 0; i < 4; ++i) {
        int u = tid * 4 + i;
        uint4 a = A[u], b = B[u];
        uint4 o;
        o.x = radd2(a.x, b.x);
        o.y = radd2(a.y, b.y);
        o.z = radd2(a.z, b.z);
        o.w = radd2(a.w, b.w);
        int px = u >> 3, g = u & 7;
        ldsZ[px * 8 + (g ^ (px & 7))] = o;
    }
}

__global__ __launch_bounds__(512, 4)
void pair_mfma_k(const uint4* __restrict__ Abf, const uint4* __restrict__ Bbf,
                 const uint4* __restrict__ Agbf, const uint4* __restrict__ Bgbf,
                 const uint4* __restrict__ W2, const uint4* __restrict__ Wg2,
                 const float* __restrict__ b2, const float* __restrict__ bg2,
                 unsigned short* __restrict__ partials)
{
    __shared__ uint4 ldsZ[2048];
    const int bi   = blockIdx.x;          // 0..399
    const int imgb = bi / 10;
    const int s    = bi % 10;
    const int n    = imgb / 20;
    const int tid  = threadIdx.x;
    const int lane = tid & 63, wv = tid >> 6;
    const int l15 = lane & 15, l4 = lane >> 4;

    f32x4 zz = {0.f, 0.f, 0.f, 0.f};
    f32x4 accout[2][4];
#pragma unroll
    for (int r = 0; r < 2; ++r)
#pragma unroll
        for (int o = 0; o < 4; ++o) accout[r][o] = zz;

    for (int ia = 0; ia < 2; ++ia) {
        const int imga = n * 20 + s * 2 + ia;

        build_z(ldsZ, Abf + imgb * 2048, Bbf + imga * 2048, tid);
        __syncthreads();
        f32x4 accm[2][4];
#pragma unroll
        for (int r = 0; r < 2; ++r)
#pragma unroll
            for (int o = 0; o < 4; ++o) accm[r][o] = zz;
        conv_tiles2(ldsZ, W2, wv * 2, lane, accm);
        __syncthreads();

        build_z(ldsZ, Agbf + imgb * 2048, Bgbf + imga * 2048, tid);
        __syncthreads();
        f32x4 accg[2][4];
#pragma unroll
        for (int r = 0; r < 2; ++r)
#pragma unroll
            for (int o = 0; o < 4; ++o) accg[r][o] = zz;
        conv_tiles2(ldsZ, Wg2, wv * 2, lane, accg);
        __syncthreads();

#pragma unroll
        for (int oct = 0; oct < 4; ++oct) {
            const float bm = b2[oct * 16 + l15];
            const float bg = bg2[oct * 16 + l15];
#pragma unroll
            for (int r = 0; r < 2; ++r)
#pragma unroll
                for (int e = 0; e < 4; ++e) {
                    float m  = accm[r][oct][e] + bm;
                    float gt = accg[r][oct][e] + bg;
                    accout[r][oct][e] += m * (1.f / (1.f + __expf(-gt)));
                }
        }
    }

    const int base = (s * NIMG + imgb) * (PXI * CH);
#pragma unroll
    for (int oct = 0; oct < 4; ++oct)
#pragma unroll
        for (int r = 0; r < 2; ++r)
#pragma unroll
            for (int e = 0; e < 4; ++e) {
                const int px = (wv * 2 + r) * 16 + l4 * 4 + e;
                partials[base + px * CH + oct * 16 + l15] = f2bf(accout[r][oct][e]);
            }
}

// ---------------------------------------------------------------------------
// Merged prep: weight repack (blocks 0..1583) + X padding (blocks 1584..4143)
// ---------------------------------------------------------------------------
struct WPrep { const float* src; unsigned short* dst; int cin_src; int cioff; int nvalid; };
struct WPrepBatch { WPrep w[11]; };

__global__ __launch_bounds__(256)
void prep_k(WPrepBatch wb, const float* __restrict__ x, const float* __restrict__ t,
            unsigned short* __restrict__ Xpad)
{
    const int bx = blockIdx.x;
    if (bx < 1584) {
        const WPrep p = wb.w[bx / 144];
        const int idx = (bx % 144) * 256 + threadIdx.x;   // 0..36863
        const int kk = idx >> 12;
        const int oc = (idx >> 6) & 63;
        const int ci = idx & 63;
        float v = 0.f;
        if (ci < p.nvalid)
            v = p.src[(oc * p.cin_src + p.cioff + ci) * 9 + kk];
        p.dst[idx] = f2bf(v);
    } else {
        const int idx = (bx - 1584) * 256 + threadIdx.x;  // 0..655359
        const int img = idx >> 14;
        const int px  = (idx >> 6) & 255;
        const int ch  = idx & 63;
        float v;
        if (ch == 0)       v = t[0];
        else if (ch <= 32) v = x[((img * 32) + (ch - 1)) * PXI + px];
        else               v = 0.f;
        Xpad[idx] = f2bf(v);
    }
}

// ---------------------------------------------------------------------------
// Final: out[img][oc][px] = u*sigmoid(ug) + (sum_s partials[s])/19,
// with LDS transpose so both global read and write are coalesced.
// ---------------------------------------------------------------------------
__global__ __launch_bounds__(512)
void final_k(const unsigned short* __restrict__ u_lin,
             const unsigned short* __restrict__ ug_lin,
             const unsigned short* __restrict__ P,
             float* __restrict__ out)
{
    __shared__ float buf[PXI * 65];
    const int img = blockIdx.x;
    const int tid = threadIdx.x;

#pragma unroll
    for (int i = 0; i < 32; ++i) {
        const int idx = i * 512 + tid;          // [px][oc], oc innermost
        const int px = idx >> 6, oc = idx & 63;
        float ssum = 0.f;
#pragma unroll
        for (int sl = 0; sl < 10; ++sl)
            ssum += bfu2f(P[(sl * NIMG + img) * (PXI * CH) + idx]);
        const float u = bfu2f(u_lin[img * (PXI * CH) + idx]);
        const float g = bfu2f(ug_lin[img * (PXI * CH) + idx]);
        buf[px * 65 + oc] = u * (1.f / (1.f + __expf(-g))) + ssum * (1.f / 19.f);
    }
    __syncthreads();
#pragma unroll
    for (int i = 0; i < 32; ++i) {
        const int j = i * 512 + tid;            // [oc][px], px innermost
        const int oc = j >> 8, px = j & 255;
        out[img * (PXI * CH) + j] = buf[px * 65 + oc];
    }
}

// ---------------------------------------------------------------------------
extern "C" void kernel_launch(void* const* d_in, const int* in_sizes, int n_in,
                              void* d_out, int out_size, void* d_ws, size_t ws_size,
                              hipStream_t stream)
{
    const float* t     = (const float*)d_in[0];
    const float* x     = (const float*)d_in[1];
    const float* w_map = (const float*)d_in[2];
    const float* b_map = (const float*)d_in[3];
    const float* w_u1  = (const float*)d_in[4];
    const float* b_u1  = (const float*)d_in[5];
    const float* w_u2  = (const float*)d_in[6];
    const float* b_u2  = (const float*)d_in[7];
    const float* w_ug1 = (const float*)d_in[8];
    const float* b_ug1 = (const float*)d_in[9];
    const float* w_ug2 = (const float*)d_in[10];
    const float* b_ug2 = (const float*)d_in[11];
    const float* w_b1  = (const float*)d_in[12];
    const float* b_b1  = (const float*)d_in[13];
    const float* w_b2  = (const float*)d_in[14];
    const float* b_b2  = (const float*)d_in[15];
    const float* w_bg1 = (const float*)d_in[16];
    const float* b_bg1 = (const float*)d_in[17];
    const float* w_bg2 = (const float*)d_in[18];
    const float* b_bg2 = (const float*)d_in[19];

    float* out = (float*)d_out;
    char* ws = (char*)d_ws;

    const size_t ABYTES = (size_t)SB_ELEM * 2;      // 1,310,720 B per bf16 tensor

    // Partials (10 bf16 slabs) overlay slabs 0..9; Xpad/h/p1/pg1 live in the
    // first 4 of them and are dead before pair_mfma_k runs (stream order).
    unsigned short* partials = (unsigned short*)(ws);
    unsigned short* Xpad   = (unsigned short*)(ws + 0 * ABYTES);
    unsigned short* h      = (unsigned short*)(ws + 1 * ABYTES);
    unsigned short* p1     = (unsigned short*)(ws + 2 * ABYTES);
    unsigned short* pg1    = (unsigned short*)(ws + 3 * ABYTES);
    unsigned short* u_lin  = (unsigned short*)(ws + 10 * ABYTES);
    unsigned short* ug_lin = (unsigned short*)(ws + 11 * ABYTES);
    unsigned short* Abuf   = (unsigned short*)(ws + 12 * ABYTES);
    unsigned short* Bbuf   = (unsigned short*)(ws + 13 * ABYTES);
    unsigned short* Agbuf  = (unsigned short*)(ws + 14 * ABYTES);
    unsigned short* Bgbuf  = (unsigned short*)(ws + 15 * ABYTES);
    char* wbase = ws + 16 * ABYTES;                 // 20.97 MB
    const size_t WBYTES = 9 * 64 * 64 * 2;          // 73,728 B per weight tensor
    unsigned short* Wmap  = (unsigned short*)(wbase + 0 * WBYTES);
    unsigned short* Wu1   = (unsigned short*)(wbase + 1 * WBYTES);
    unsigned short* Wu2   = (unsigned short*)(wbase + 2 * WBYTES);
    unsigned short* Wug1  = (unsigned short*)(wbase + 3 * WBYTES);
    unsigned short* Wug2  = (unsigned short*)(wbase + 4 * WBYTES);
    unsigned short* Wb1a  = (unsigned short*)(wbase + 5 * WBYTES);
    unsigned short* Wb1b  = (unsigned short*)(wbase + 6 * WBYTES);
    unsigned short* Wbg1a = (unsigned short*)(wbase + 7 * WBYTES);
    unsigned short* Wbg1b = (unsigned short*)(wbase + 8 * WBYTES);
    unsigned short* Wb2   = (unsigned short*)(wbase + 9 * WBYTES);
    unsigned short* Wbg2  = (unsigned short*)(wbase + 10 * WBYTES);

    // --- prep: weights repack + Xpad build (one launch) ---
    WPrepBatch wb;
    wb.w[0]  = { w_map, Wmap,  33,  0, 33 };
    wb.w[1]  = { w_u1,  Wu1,   64,  0, 64 };
    wb.w[2]  = { w_u2,  Wu2,   64,  0, 64 };
    wb.w[3]  = { w_ug1, Wug1,  64,  0, 64 };
    wb.w[4]  = { w_ug2, Wug2,  64,  0, 64 };
    wb.w[5]  = { w_b1,  Wb1a, 128,  0, 64 };
    wb.w[6]  = { w_b1,  Wb1b, 128, 64, 64 };
    wb.w[7]  = { w_bg1, Wbg1a,128,  0, 64 };
    wb.w[8]  = { w_bg1, Wbg1b,128, 64, 64 };
    wb.w[9]  = { w_b2,  Wb2,   64,  0, 64 };
    wb.w[10] = { w_bg2, Wbg2,  64,  0, 64 };
    prep_k<<<dim3(1584 + 2560), dim3(256), 0, stream>>>(wb, x, t, Xpad);

    // --- map conv: h = conv(Xpad, w_map) + b_map ---
    ConvBatch cm{};
    cm.d[0] = { (const uint4*)Xpad, (const uint4*)Wmap, b_map, h, 0 };
    for (int i = 1; i < 6; ++i) cm.d[i] = cm.d[0];
    conv_mfma_k<<<dim3(NIMG, 1), dim3(512), 0, stream>>>(cm);

    // --- stage 1: six convs from h ---
    ConvBatch c1{};
    c1.d[0] = { (const uint4*)h, (const uint4*)Wu1,   b_u1,  p1,    1 };
    c1.d[1] = { (const uint4*)h, (const uint4*)Wug1,  b_ug1, pg1,   1 };
    c1.d[2] = { (const uint4*)h, (const uint4*)Wb1a,  b_b1,  Abuf,  0 };
    c1.d[3] = { (const uint4*)h, (const uint4*)Wb1b,  nullptr, Bbuf, 0 };
    c1.d[4] = { (const uint4*)h, (const uint4*)Wbg1a, b_bg1, Agbuf, 0 };
    c1.d[5] = { (const uint4*)h, (const uint4*)Wbg1b, nullptr, Bgbuf, 0 };
    conv_mfma_k<<<dim3(NIMG, 6), dim3(512), 0, stream>>>(c1);

    // --- stage 2: u_lin, ug_lin ---
    ConvBatch c2{};
    c2.d[0] = { (const uint4*)p1,  (const uint4*)Wu2,  b_u2,  u_lin,  0 };
    c2.d[1] = { (const uint4*)pg1, (const uint4*)Wug2, b_ug2, ug_lin, 0 };
    for (int i = 2; i < 6; ++i) c2.d[i] = c2.d[0];
    conv_mfma_k<<<dim3(NIMG, 2), dim3(512), 0, stream>>>(c2);

    // --- pairwise messages -> bf16 partial slabs (no atomics) ---
    pair_mfma_k<<<dim3(400), dim3(512), 0, stream>>>(
        (const uint4*)Abuf, (const uint4*)Bbuf, (const uint4*)Agbuf, (const uint4*)Bgbuf,
        (const uint4*)Wb2, (const uint4*)Wbg2, b_b2, b_bg2, partials);

    // --- final combine + transpose to [img][oc][px] ---
    final_k<<<dim3(NIMG), dim3(512), 0, stream>>>(u_lin, ug_lin, partials, out);
}

// Round 4
// 167.851 us; speedup vs baseline: 4.0993x; 4.0993x over previous
//
#include <hip/hip_runtime.h>
#include <math.h>

// N=2, K=20 -> 40 images; C=64 channels; 16x16 images (256 px).
#define NIMG 40
#define PXI  256
#define CH   64
#define SB_ELEM (NIMG * PXI * CH)   // 655360 elems per activation tensor

typedef __bf16 bf16x8 __attribute__((ext_vector_type(8)));
typedef float  f32x4  __attribute__((ext_vector_type(4)));

static __device__ __forceinline__ unsigned short f2bf(float f) {
    unsigned u = __builtin_bit_cast(unsigned, f);
    u += 0x7fffu + ((u >> 16) & 1u);          // RNE
    return (unsigned short)(u >> 16);
}
static __device__ __forceinline__ unsigned pk2(float a, float b) {
    return (unsigned)f2bf(a) | ((unsigned)f2bf(b) << 16);
}
static __device__ __forceinline__ float bfu2f(unsigned hs) {  // bf16 bits in low 16
    unsigned u = (hs & 0xffffu) << 16;
    return __builtin_bit_cast(float, u);
}

// ---------------------------------------------------------------------------
// Single-source conv core (stage-1/2 convs): one wave does rows {y0,y0+1}
// x 4 oc-tiles from swizzled LDS Z and Wt bf16 [9][64 oc][64 ci].
// LDS 16B-slot index = pix*8 + (g ^ (pix&7)), g = ci/8.  (T2 swizzle)
// ---------------------------------------------------------------------------
static __device__ __forceinline__ void conv_tiles2(const uint4* __restrict__ ldsZ,
                                                   const uint4* __restrict__ Wt,
                                                   int y0, int lane, f32x4 acc[2][4])
{
    const int l15 = lane & 15;
    const int l4  = lane >> 4;
#pragma unroll
    for (int khalf = 0; khalf < 2; ++khalf) {
        const int g = khalf * 4 + l4;
#pragma unroll
        for (int kk = 0; kk < 9; ++kk) {
            const int ky = kk / 3 - 1;
            const int kx = kk % 3 - 1;
            bf16x8 bfrag[4];
#pragma unroll
            for (int oct = 0; oct < 4; ++oct)
                bfrag[oct] = __builtin_bit_cast(bf16x8, Wt[(kk * 64 + oct * 16 + l15) * 8 + g]);
#pragma unroll
            for (int r = 0; r < 2; ++r) {
                const int yy = y0 + r + ky;
                const int xx = l15 + kx;
                const bool inb = ((unsigned)yy < 16u) && ((unsigned)xx < 16u);
                const int pix = inb ? (yy * 16 + xx) : 0;
                uint4 av = ldsZ[pix * 8 + (g ^ (pix & 7))];
                if (!inb) { av.x = 0u; av.y = 0u; av.z = 0u; av.w = 0u; }
                bf16x8 afrag = __builtin_bit_cast(bf16x8, av);
#pragma unroll
                for (int oct = 0; oct < 4; ++oct)
                    acc[r][oct] = __builtin_amdgcn_mfma_f32_16x16x32_bf16(
                        afrag, bfrag[oct], acc[r][oct], 0, 0, 0);
            }
        }
    }
}

// ---------------------------------------------------------------------------
// Dual-source conv core for the pair kernel: each weight fragment feeds
// 2 sources x 2 rows = 4 MFMAs (halves weight L2 traffic).
// ---------------------------------------------------------------------------
static __device__ __forceinline__ void conv_tiles2_dual(
    const uint4* __restrict__ Z0, const uint4* __restrict__ Z1,
    const uint4* __restrict__ Wt, int y0, int lane, f32x4 acc[2][2][4])
{
    const int l15 = lane & 15;
    const int l4  = lane >> 4;
#pragma unroll
    for (int khalf = 0; khalf < 2; ++khalf) {
        const int g = khalf * 4 + l4;
#pragma unroll
        for (int kk = 0; kk < 9; ++kk) {
            const int ky = kk / 3 - 1;
            const int kx = kk % 3 - 1;
            bf16x8 bfrag[4];
#pragma unroll
            for (int oct = 0; oct < 4; ++oct)
                bfrag[oct] = __builtin_bit_cast(bf16x8, Wt[(kk * 64 + oct * 16 + l15) * 8 + g]);
#pragma unroll
            for (int r = 0; r < 2; ++r) {
                const int yy = y0 + r + ky;
                const int xx = l15 + kx;
                const bool inb = ((unsigned)yy < 16u) && ((unsigned)xx < 16u);
                const int pix = inb ? (yy * 16 + xx) : 0;
                const int slot = pix * 8 + (g ^ (pix & 7));
                uint4 a0 = Z0[slot];
                uint4 a1 = Z1[slot];
                if (!inb) {
                    a0.x = a0.y = a0.z = a0.w = 0u;
                    a1.x = a1.y = a1.z = a1.w = 0u;
                }
                bf16x8 f0 = __builtin_bit_cast(bf16x8, a0);
                bf16x8 f1 = __builtin_bit_cast(bf16x8, a1);
#pragma unroll
                for (int oct = 0; oct < 4; ++oct) {
                    acc[0][r][oct] = __builtin_amdgcn_mfma_f32_16x16x32_bf16(
                        f0, bfrag[oct], acc[0][r][oct], 0, 0, 0);
                    acc[1][r][oct] = __builtin_amdgcn_mfma_f32_16x16x32_bf16(
                        f1, bfrag[oct], acc[1][r][oct], 0, 0, 0);
                }
            }
        }
    }
}

// ---------------------------------------------------------------------------
// Generic MFMA conv: X bf16 [img][256][64] -> out bf16 [img][256][64]
// ---------------------------------------------------------------------------
struct ConvDesc {
    const uint4* X;
    const uint4* W;
    const float* bias;      // nullptr -> no bias
    unsigned short* out;
    int relu;
};
struct ConvBatch { ConvDesc d[6]; };

__global__ __launch_bounds__(512)
void conv_mfma_k(ConvBatch cb)
{
    __shared__ uint4 ldsZ[2048];
    const ConvDesc d = cb.d[blockIdx.y];
    const int img = blockIdx.x;
    const int tid = threadIdx.x;

    const uint4* Xi = d.X + img * 2048;
#pragma unroll
    for (int i = 0; i < 4; ++i) {
        int u = i * 512 + tid;
        int px = u >> 3, g = u & 7;
        ldsZ[px * 8 + (g ^ (px & 7))] = Xi[u];
    }
    __syncthreads();

    const int lane = tid & 63, wv = tid >> 6;
    const int l15 = lane & 15, l4 = lane >> 4;
    f32x4 zz = {0.f, 0.f, 0.f, 0.f};
    f32x4 acc[2][4];
#pragma unroll
    for (int r = 0; r < 2; ++r)
#pragma unroll
        for (int o = 0; o < 4; ++o) acc[r][o] = zz;

    conv_tiles2(ldsZ, d.W, wv * 2, lane, acc);

#pragma unroll
    for (int oct = 0; oct < 4; ++oct) {
        const int oc = oct * 16 + l15;
        const float b = d.bias ? d.bias[oc] : 0.f;
#pragma unroll
        for (int r = 0; r < 2; ++r)
#pragma unroll
            for (int e = 0; e < 4; ++e) {
                float v = acc[r][oct][e] + b;
                if (d.relu) v = fmaxf(v, 0.f);
                const int px = (wv * 2 + r) * 16 + l4 * 4 + e;
                d.out[(img * PXI + px) * CH + oc] = f2bf(v);
            }
    }
}

// ---------------------------------------------------------------------------
// Pair kernel: block bi -> imgb = bi/10, split s = bi%10 handling 2 sources.
// Both sources' Z staged in LDS; msg pass (both) -> bf16 reg stash ->
// gate pass (both) -> combine -> uint2 stores to partials[s][img][oc][px].
// ---------------------------------------------------------------------------
static __device__ __forceinline__ uint4 relu_add4(uint4 a, uint4 b) {
    uint4 o;
    unsigned* ap = &a.x; unsigned* bp = &b.x; unsigned* op = &o.x;
#pragma unroll
    for (int w = 0; w < 4; ++w) {
        float a0 = __builtin_bit_cast(float, ap[w] << 16);
        float a1 = __builtin_bit_cast(float, ap[w] & 0xffff0000u);
        float b0 = __builtin_bit_cast(float, bp[w] << 16);
        float b1 = __builtin_bit_cast(float, bp[w] & 0xffff0000u);
        op[w] = pk2(fmaxf(a0 + b0, 0.f), fmaxf(a1 + b1, 0.f));
    }
    return o;
}

__global__ __launch_bounds__(512)
void pair_mfma_k(const uint4* __restrict__ Abf, const uint4* __restrict__ Bbf,
                 const uint4* __restrict__ Agbf, const uint4* __restrict__ Bgbf,
                 const uint4* __restrict__ W2, const uint4* __restrict__ Wg2,
                 const float* __restrict__ b2, const float* __restrict__ bg2,
                 unsigned short* __restrict__ partials)
{
    __shared__ uint4 Z[2][2048];
    const int bi   = blockIdx.x;          // 0..399
    const int imgb = bi / 10;
    const int s    = bi % 10;
    const int n    = imgb / 20;
    const int tid  = threadIdx.x;
    const int lane = tid & 63, wv = tid >> 6;
    const int l15 = lane & 15, l4 = lane >> 4;
    const int imga0 = n * 20 + s * 2;

    // ---- build msg inputs: Z0 = relu(A[b]+B[a0]), Z1 = relu(A[b]+B[a1]) ----
    {
        const uint4* Ap = Abf + imgb * 2048;
        const uint4* B0 = Bbf + imga0 * 2048;
        const uint4* B1 = B0 + 2048;
#pragma unroll
        for (int i = 0; i < 4; ++i) {
            int u = i * 512 + tid;
            uint4 a = Ap[u];
            int slot = (u >> 3) * 8 + ((u & 7) ^ ((u >> 3) & 7));
            Z[0][slot] = relu_add4(a, B0[u]);
            Z[1][slot] = relu_add4(a, B1[u]);
        }
    }
    __syncthreads();

    f32x4 zz = {0.f, 0.f, 0.f, 0.f};
    f32x4 acc[2][2][4];
#pragma unroll
    for (int ia = 0; ia < 2; ++ia)
#pragma unroll
        for (int r = 0; r < 2; ++r)
#pragma unroll
            for (int o = 0; o < 4; ++o) acc[ia][r][o] = zz;

    conv_tiles2_dual(Z[0], Z[1], W2, wv * 2, lane, acc);

    // ---- stash msg (+bias) as bf16 in registers ----
    float bmv[4];
#pragma unroll
    for (int oct = 0; oct < 4; ++oct) bmv[oct] = b2[oct * 16 + l15];
    unsigned mst[2][2][4][2];
#pragma unroll
    for (int ia = 0; ia < 2; ++ia)
#pragma unroll
        for (int r = 0; r < 2; ++r)
#pragma unroll
            for (int oct = 0; oct < 4; ++oct) {
                mst[ia][r][oct][0] = pk2(acc[ia][r][oct][0] + bmv[oct],
                                         acc[ia][r][oct][1] + bmv[oct]);
                mst[ia][r][oct][1] = pk2(acc[ia][r][oct][2] + bmv[oct],
                                         acc[ia][r][oct][3] + bmv[oct]);
            }

    __syncthreads();   // everyone done reading Z before overwrite

    // ---- build gate inputs ----
    {
        const uint4* Ap = Agbf + imgb * 2048;
        const uint4* B0 = Bgbf + imga0 * 2048;
        const uint4* B1 = B0 + 2048;
#pragma unroll
        for (int i = 0; i < 4; ++i) {
            int u = i * 512 + tid;
            uint4 a = Ap[u];
            int slot = (u >> 3) * 8 + ((u & 7) ^ ((u >> 3) & 7));
            Z[0][slot] = relu_add4(a, B0[u]);
            Z[1][slot] = relu_add4(a, B1[u]);
        }
    }
    __syncthreads();

#pragma unroll
    for (int ia = 0; ia < 2; ++ia)
#pragma unroll
        for (int r = 0; r < 2; ++r)
#pragma unroll
            for (int o = 0; o < 4; ++o) acc[ia][r][o] = zz;

    conv_tiles2_dual(Z[0], Z[1], Wg2, wv * 2, lane, acc);

    // ---- combine: out = sum_ia msg * sigmoid(gate), store 8B per lane ----
    float bgv[4];
#pragma unroll
    for (int oct = 0; oct < 4; ++oct) bgv[oct] = bg2[oct * 16 + l15];

    const int base = (s * NIMG + imgb) * (PXI * CH);
#pragma unroll
    for (int r = 0; r < 2; ++r)
#pragma unroll
        for (int oct = 0; oct < 4; ++oct) {
            float o[4] = {0.f, 0.f, 0.f, 0.f};
#pragma unroll
            for (int ia = 0; ia < 2; ++ia)
#pragma unroll
                for (int e = 0; e < 4; ++e) {
                    float gt = acc[ia][r][oct][e] + bgv[oct];
                    float msg = bfu2f(mst[ia][r][oct][e >> 1] >> ((e & 1) * 16));
                    o[e] += msg * (1.f / (1.f + __expf(-gt)));
                }
            uint2 pkd;
            pkd.x = pk2(o[0], o[1]);
            pkd.y = pk2(o[2], o[3]);
            const int px0 = (wv * 2 + r) * 16 + l4 * 4;
            const int oc  = oct * 16 + l15;
            *(uint2*)&partials[base + oc * PXI + px0] = pkd;
        }
}

// ---------------------------------------------------------------------------
// Merged prep: weight repack (blocks 0..1583) + X padding (blocks 1584..4143)
// ---------------------------------------------------------------------------
struct WPrep { const float* src; unsigned short* dst; int cin_src; int cioff; int nvalid; };
struct WPrepBatch { WPrep w[11]; };

__global__ __launch_bounds__(256)
void prep_k(WPrepBatch wb, const float* __restrict__ x, const float* __restrict__ t,
            unsigned short* __restrict__ Xpad)
{
    const int bx = blockIdx.x;
    if (bx < 1584) {
        const WPrep p = wb.w[bx / 144];
        const int idx = (bx % 144) * 256 + threadIdx.x;   // 0..36863
        const int kk = idx >> 12;
        const int oc = (idx >> 6) & 63;
        const int ci = idx & 63;
        float v = 0.f;
        if (ci < p.nvalid)
            v = p.src[(oc * p.cin_src + p.cioff + ci) * 9 + kk];
        p.dst[idx] = f2bf(v);
    } else {
        const int idx = (bx - 1584) * 256 + threadIdx.x;  // 0..655359
        const int img = idx >> 14;
        const int px  = (idx >> 6) & 255;
        const int ch  = idx & 63;
        float v;
        if (ch == 0)       v = t[0];
        else if (ch <= 32) v = x[((img * 32) + (ch - 1)) * PXI + px];
        else               v = 0.f;
        Xpad[idx] = f2bf(v);
    }
}

// ---------------------------------------------------------------------------
// Final: out[img][oc][px] = u*sigmoid(ug) + (sum_s partials[s])/19.
// u/ug are [px][oc] (transposed via LDS); partials already [oc][px].
// ---------------------------------------------------------------------------
__global__ __launch_bounds__(512)
void final_k(const unsigned short* __restrict__ u_lin,
             const unsigned short* __restrict__ ug_lin,
             const unsigned short* __restrict__ P,
             float* __restrict__ out)
{
    __shared__ float buf[PXI * 65];
    const int img = blockIdx.x;
    const int tid = threadIdx.x;

#pragma unroll
    for (int i = 0; i < 32; ++i) {
        const int idx = i * 512 + tid;          // [px][oc], oc innermost
        const int px = idx >> 6, oc = idx & 63;
        const float u = bfu2f(u_lin[img * (PXI * CH) + idx]);
        const float g = bfu2f(ug_lin[img * (PXI * CH) + idx]);
        buf[px * 65 + oc] = u * (1.f / (1.f + __expf(-g)));
    }
    __syncthreads();
#pragma unroll
    for (int i = 0; i < 32; ++i) {
        const int j = i * 512 + tid;            // [oc][px], px innermost
        const int oc = j >> 8, px = j & 255;
        float ssum = 0.f;
#pragma unroll
        for (int sl = 0; sl < 10; ++sl)
            ssum += bfu2f(P[(sl * NIMG + img) * (PXI * CH) + j]);
        out[img * (PXI * CH) + j] = buf[px * 65 + oc] + ssum * (1.f / 19.f);
    }
}

// ---------------------------------------------------------------------------
extern "C" void kernel_launch(void* const* d_in, const int* in_sizes, int n_in,
                              void* d_out, int out_size, void* d_ws, size_t ws_size,
                              hipStream_t stream)
{
    const float* t     = (const float*)d_in[0];
    const float* x     = (const float*)d_in[1];
    const float* w_map = (const float*)d_in[2];
    const float* b_map = (const float*)d_in[3];
    const float* w_u1  = (const float*)d_in[4];
    const float* b_u1  = (const float*)d_in[5];
    const float* w_u2  = (const float*)d_in[6];
    const float* b_u2  = (const float*)d_in[7];
    const float* w_ug1 = (const float*)d_in[8];
    const float* b_ug1 = (const float*)d_in[9];
    const float* w_ug2 = (const float*)d_in[10];
    const float* b_ug2 = (const float*)d_in[11];
    const float* w_b1  = (const float*)d_in[12];
    const float* b_b1  = (const float*)d_in[13];
    const float* w_b2  = (const float*)d_in[14];
    const float* b_b2  = (const float*)d_in[15];
    const float* w_bg1 = (const float*)d_in[16];
    const float* b_bg1 = (const float*)d_in[17];
    const float* w_bg2 = (const float*)d_in[18];
    const float* b_bg2 = (const float*)d_in[19];

    float* out = (float*)d_out;
    char* ws = (char*)d_ws;

    const size_t ABYTES = (size_t)SB_ELEM * 2;      // 1,310,720 B per bf16 tensor

    // Partials (10 bf16 slabs) overlay slabs 0..9; Xpad/h/p1/pg1 live in the
    // first 4 and are dead before pair_mfma_k runs (stream order).
    unsigned short* partials = (unsigned short*)(ws);
    unsigned short* Xpad   = (unsigned short*)(ws + 0 * ABYTES);
    unsigned short* h      = (unsigned short*)(ws + 1 * ABYTES);
    unsigned short* p1     = (unsigned short*)(ws + 2 * ABYTES);
    unsigned short* pg1    = (unsigned short*)(ws + 3 * ABYTES);
    unsigned short* u_lin  = (unsigned short*)(ws + 10 * ABYTES);
    unsigned short* ug_lin = (unsigned short*)(ws + 11 * ABYTES);
    unsigned short* Abuf   = (unsigned short*)(ws + 12 * ABYTES);
    unsigned short* Bbuf   = (unsigned short*)(ws + 13 * ABYTES);
    unsigned short* Agbuf  = (unsigned short*)(ws + 14 * ABYTES);
    unsigned short* Bgbuf  = (unsigned short*)(ws + 15 * ABYTES);
    char* wbase = ws + 16 * ABYTES;                 // ~21 MB
    const size_t WBYTES = 9 * 64 * 64 * 2;          // 73,728 B per weight tensor
    unsigned short* Wmap  = (unsigned short*)(wbase + 0 * WBYTES);
    unsigned short* Wu1   = (unsigned short*)(wbase + 1 * WBYTES);
    unsigned short* Wu2   = (unsigned short*)(wbase + 2 * WBYTES);
    unsigned short* Wug1  = (unsigned short*)(wbase + 3 * WBYTES);
    unsigned short* Wug2  = (unsigned short*)(wbase + 4 * WBYTES);
    unsigned short* Wb1a  = (unsigned short*)(wbase + 5 * WBYTES);
    unsigned short* Wb1b  = (unsigned short*)(wbase + 6 * WBYTES);
    unsigned short* Wbg1a = (unsigned short*)(wbase + 7 * WBYTES);
    unsigned short* Wbg1b = (unsigned short*)(wbase + 8 * WBYTES);
    unsigned short* Wb2   = (unsigned short*)(wbase + 9 * WBYTES);
    unsigned short* Wbg2  = (unsigned short*)(wbase + 10 * WBYTES);

    // --- prep: weights repack + Xpad build (one launch) ---
    WPrepBatch wb;
    wb.w[0]  = { w_map, Wmap,  33,  0, 33 };
    wb.w[1]  = { w_u1,  Wu1,   64,  0, 64 };
    wb.w[2]  = { w_u2,  Wu2,   64,  0, 64 };
    wb.w[3]  = { w_ug1, Wug1,  64,  0, 64 };
    wb.w[4]  = { w_ug2, Wug2,  64,  0, 64 };
    wb.w[5]  = { w_b1,  Wb1a, 128,  0, 64 };
    wb.w[6]  = { w_b1,  Wb1b, 128, 64, 64 };
    wb.w[7]  = { w_bg1, Wbg1a,128,  0, 64 };
    wb.w[8]  = { w_bg1, Wbg1b,128, 64, 64 };
    wb.w[9]  = { w_b2,  Wb2,   64,  0, 64 };
    wb.w[10] = { w_bg2, Wbg2,  64,  0, 64 };
    prep_k<<<dim3(1584 + 2560), dim3(256), 0, stream>>>(wb, x, t, Xpad);

    // --- map conv: h = conv(Xpad, w_map) + b_map ---
    ConvBatch cm{};
    cm.d[0] = { (const uint4*)Xpad, (const uint4*)Wmap, b_map, h, 0 };
    for (int i = 1; i < 6; ++i) cm.d[i] = cm.d[0];
    conv_mfma_k<<<dim3(NIMG, 1), dim3(512), 0, stream>>>(cm);

    // --- stage 1: six convs from h ---
    ConvBatch c1{};
    c1.d[0] = { (const uint4*)h, (const uint4*)Wu1,   b_u1,  p1,    1 };
    c1.d[1] = { (const uint4*)h, (const uint4*)Wug1,  b_ug1, pg1,   1 };
    c1.d[2] = { (const uint4*)h, (const uint4*)Wb1a,  b_b1,  Abuf,  0 };
    c1.d[3] = { (const uint4*)h, (const uint4*)Wb1b,  nullptr, Bbuf, 0 };
    c1.d[4] = { (const uint4*)h, (const uint4*)Wbg1a, b_bg1, Agbuf, 0 };
    c1.d[5] = { (const uint4*)h, (const uint4*)Wbg1b, nullptr, Bgbuf, 0 };
    conv_mfma_k<<<dim3(NIMG, 6), dim3(512), 0, stream>>>(c1);

    // --- stage 2: u_lin, ug_lin ---
    ConvBatch c2{};
    c2.d[0] = { (const uint4*)p1,  (const uint4*)Wu2,  b_u2,  u_lin,  0 };
    c2.d[1] = { (const uint4*)pg1, (const uint4*)Wug2, b_ug2, ug_lin, 0 };
    for (int i = 2; i < 6; ++i) c2.d[i] = c2.d[0];
    conv_mfma_k<<<dim3(NIMG, 2), dim3(512), 0, stream>>>(c2);

    // --- pairwise messages -> bf16 partial slabs (no atomics) ---
    pair_mfma_k<<<dim3(400), dim3(512), 0, stream>>>(
        (const uint4*)Abuf, (const uint4*)Bbuf, (const uint4*)Agbuf, (const uint4*)Bgbuf,
        (const uint4*)Wb2, (const uint4*)Wbg2, b_b2, b_bg2, partials);

    // --- final combine ---
    final_k<<<dim3(NIMG), dim3(512), 0, stream>>>(u_lin, ug_lin, partials, out);
}